// Round 19
// baseline (1455.067 us; speedup 1.0000x reference)
//
#include <hip/hip_runtime.h>
#include <cstddef>

#define NFRM 247
#define NBIN 128
#define NC   32
#define NWIN 58
#define NMAT (8 * NWIN * 6)   // 2784
#define NBT  (8 * NWIN)       // 464

// ---------------- K1: STFT (16x16 split DFT, bins 1..128) ----------------
// R19: block = (b, frame), 256 threads, 4 channel-groups of 8 staged in LDS.
// Same twiddle-recurrence math as R13-18. Writes are (f,ch)-tiled -> 64B-coalesced;
// XCD swizzle by b pins x[b] (2MB) in one XCD's L2. Y as re/im planes, stride 273
// (odd) -> stage-B reads are <=4-way banked instead of 8-way.
// spec layout: (b, frame, f-1, c) float2 (unchanged for k_csd).
__global__ __launch_bounds__(256) void k_stft(const float* __restrict__ x,
                                              float2* __restrict__ spec) {
  const int bid = blockIdx.x;          // 8*247 blocks
  const int b   = bid & 7;             // batch -> XCD (bijective: 1976 = 8*247)
  const int fr  = bid >> 3;
  const int tid = threadIdx.x;

  __shared__ float w[256];
  __shared__ float xw[8][257];
  __shared__ float Yre[8][273];
  __shared__ float Yim[8][273];

  // hann window (np.hanning: periodic=False) * 1/||w||
  w[tid] = (0.5f - 0.5f * __cosf((float)tid * 0.024639942f)) * 0.10226200f;

  float2* ob = spec + ((size_t)b * NFRM + fr) * (NBIN * NC);
  const float* xb = x + ((size_t)b * 32) * 16000 + fr * 64;

  for (int g = 0; g < 4; ++g) {        // channel groups of 8
    __syncthreads();                   // w ready (g=0) / prev group done reading
    // load + window: xw[ch][t] = x[b][g*8+ch][fr*64+t] * w[t]
    #pragma unroll
    for (int k = 0; k < 8; ++k) {
      const int u = tid + k * 256;
      const int ch = u >> 8, t = u & 255;
      xw[ch][t] = xb[(size_t)(g * 8 + ch) * 16000 + t] * w[t];
    }
    __syncthreads();

    // stage A: Y[ch][e], e = 16*f0+t0 : sum_t1 xw[ch][16t1+t0] * e^{-i pi f0 t1/8}
    #pragma unroll
    for (int k = 0; k < 8; ++k) {
      const int u = tid + k * 256;
      const int ch = u >> 8;           // = k
      const int e = u & 255;
      const int f0 = e >> 4, t0 = e & 15;
      float sA, cA;
      __sincosf((float)f0 * 0.39269908f, &sA, &cA);   // pi/8
      float wr = 1.f, wi = 0.f, re = 0.f, im = 0.f;
      #pragma unroll
      for (int t1 = 0; t1 < 16; ++t1) {
        const float v = xw[ch][(t1 << 4) + t0];
        re = fmaf(v, wr, re);
        im = fmaf(v, wi, im);
        const float nwr = fmaf(wi, sA, wr * cA);
        const float nwi = fmaf(-wr, sA, wi * cA);
        wr = nwr; wi = nwi;
      }
      Yre[ch][e] = re;
      Yim[ch][e] = im;
    }
    __syncthreads();

    // stage B + write: job j = (f-1)*8 + ch; f = (j>>3)+1, ch = j&7
    #pragma unroll
    for (int q = 0; q < 4; ++q) {
      const int j = tid + q * 256;
      const int ch = j & 7;
      const int f = (j >> 3) + 1;      // 1..128
      const int f0 = f & 15;
      float sB, cB;
      __sincosf((float)f * 0.024543693f, &sB, &cB);   // 2pi/256
      float wr = 1.f, wi = 0.f, re = 0.f, im = 0.f;
      #pragma unroll
      for (int t0 = 0; t0 < 16; ++t0) {
        const float yr = Yre[ch][(f0 << 4) + t0];
        const float yi = Yim[ch][(f0 << 4) + t0];
        re += yr * wr - yi * wi;
        im += yr * wi + yi * wr;
        const float nwr = fmaf(wi, sB, wr * cB);
        const float nwi = fmaf(-wr, sB, wi * cB);
        wr = nwr; wi = nwi;
      }
      ob[(size_t)(f - 1) * NC + g * 8 + ch] = make_float2(re, im);
    }
  }
}

// ---------------- K2: CSD + |.|^2 + band-slot partials ----------------
// R17/18-proven: barrier-free ring staging + pipeline; contiguous 16-bin range per
// wave, single bacc[16], band-crossing flush to per-(p,wv,band) global SLOT
// (unique owner -> non-atomic, deterministic). XCD-bijective bt swizzle.
// R19: __launch_bounds__(256,4) caps VGPR at 128 -> 4 waves/SIMD (was 168 -> 2).
// part layout: (slot, bt, i*32+j) float.
__global__ __launch_bounds__(256, 4) void k_csd(const float2* __restrict__ spec,
                                                float* __restrict__ part) {
  const int bt  = (blockIdx.x & 7) * 58 + (blockIdx.x >> 3);   // b*58 + t (swizzled)
  const int p   = blockIdx.y;          // f-half: 0 -> f 1..64, 1 -> f 65..128
  const int b   = bt / NWIN, t = bt % NWIN;
  const int tid = threadIdx.x;
  const int wv  = tid >> 6;            // wave 0..3
  const int lane = tid & 63;
  const int i0 = (lane >> 3) * 4;
  const int j0 = (lane & 7) * 4;

  __shared__ __align__(16) float2 rng[4][2][512];   // 32KB wave-private ring

  float bacc[16];
  #pragma unroll
  for (int e = 0; e < 16; ++e) bacc[e] = 0.f;

  const float2* sb = spec + (size_t)b * NFRM * NBIN * NC;
  const int fbase = 1 + 64 * p + 16 * wv;           // wave's first bin
  int slot = p ? (9 + wv) : (wv == 0 ? 0 : wv == 1 ? 4 : wv == 2 ? 6 : 7);

  #define BANDOF(f) ((f) <= 3 ? 0 : (f) <= 6 ? 1 : (f) <= 12 ? 2 : (f) <= 25 ? 3 : (f) <= 51 ? 4 : 5)
  int curband = BANDOF(fbase);

  #define FLUSH()                                                                \
    {                                                                            \
      float scl_;                                                                \
      switch (curband) {                                                         \
        case 0: case 1: scl_ = 1.f / 768.f;   break;                             \
        case 2:         scl_ = 1.f / 1536.f;  break;                             \
        case 3:         scl_ = 1.f / 3328.f;  break;                             \
        case 4:         scl_ = 1.f / 6656.f;  break;                             \
        default:        scl_ = 1.f / 19712.f; break;                             \
      }                                                                          \
      float* op_ = part + ((size_t)slot * NBT + bt) * 1024;                      \
      _Pragma("unroll")                                                          \
      for (int a = 0; a < 4; ++a)                                                \
        *(float4*)(op_ + (i0 + a) * 32 + j0) =                                   \
          make_float4(bacc[a * 4 + 0] * scl_, bacc[a * 4 + 1] * scl_,            \
                      bacc[a * 4 + 2] * scl_, bacc[a * 4 + 3] * scl_);           \
      _Pragma("unroll")                                                          \
      for (int e = 0; e < 16; ++e) bacc[e] = 0.f;                                \
    }

  #define STG_LOAD(itl, dst)                                                     \
    {                                                                            \
      const int f_ = fbase + (itl);                                              \
      const float2* fp_ = sb + (size_t)(f_ - 1) * NC;                            \
      _Pragma("unroll")                                                          \
      for (int r = 0; r < 8; ++r) {                                              \
        const int e_ = lane + r * 64;                                            \
        dst[r] = fp_[(size_t)(t * 4 + (e_ >> 5)) * (NBIN * NC) + (e_ & 31)];     \
      }                                                                          \
    }

  // prologue: stage itl=0
  {
    float2 stg[8];
    STG_LOAD(0, stg)
    #pragma unroll
    for (int r = 0; r < 8; ++r) rng[wv][0][lane + r * 64] = stg[r];
  }

  #pragma unroll 1
  for (int itl = 0; itl < 16; ++itl) {
    float2 stg2[8];
    if (itl + 1 < 16) STG_LOAD(itl + 1, stg2)

    const int f = fbase + itl;                       // wave-uniform bin
    if (f == 4 || f == 7 || f == 13 || f == 26 || f == 52) {   // band crossing
      FLUSH()
      ++slot;
      curband = BANDOF(f);
    }

    const float2* Xs = rng[wv][itl & 1];

    float accRe[16], accIm[16];
    #pragma unroll
    for (int e = 0; e < 16; ++e) { accRe[e] = 0.f; accIm[e] = 0.f; }

    #pragma unroll
    for (int s = 0; s < 16; ++s) {
      float2 xi[4], xj[4];
      #pragma unroll
      for (int a = 0; a < 4; ++a) {
        xi[a] = Xs[s * 32 + i0 + a];
        xj[a] = Xs[s * 32 + j0 + a];
      }
      #pragma unroll
      for (int a = 0; a < 4; ++a)
        #pragma unroll
        for (int d = 0; d < 4; ++d) {
          const int e = a * 4 + d;
          // M_ij += x_i * conj(x_j)
          accRe[e] = fmaf(xi[a].x, xj[d].x, fmaf(xi[a].y, xj[d].y, accRe[e]));
          accIm[e] = fmaf(xi[a].y, xj[d].x, fmaf(-xi[a].x, xj[d].y, accIm[e]));
        }
    }

    #pragma unroll
    for (int e = 0; e < 16; ++e)
      bacc[e] = fmaf(accRe[e], accRe[e], fmaf(accIm[e], accIm[e], bacc[e]));

    if (itl + 1 < 16) {
      #pragma unroll
      for (int r = 0; r < 8; ++r) rng[wv][(itl + 1) & 1][lane + r * 64] = stg2[r];
    }
  }
  FLUSH()   // final band
  #undef STG_LOAD
  #undef FLUSH
  #undef BANDOF
}

// ---------------- K3: one-sided Jacobi eig + matrix log ----------------
// R12/R15-proven core (bpermute exchange). EPS2=1e-6 [R18-validated, absmax 0.0156].
// Slot sums in fixed order (deterministic).
__global__ __launch_bounds__(64) void k_eig(const float* __restrict__ part,
                                            float* __restrict__ eigTmp) {
  const int blk  = blockIdx.x;         // matrix id = (b*58+t)*6 + k
  const int lane = threadIdx.x;
  const int h    = lane >> 5;          // half: rows [16h, 16h+16)
  const int c    = lane & 31;          // column

  const int kq = blk % 6;
  const int bt = blk / 6;
  const int s0  = (kq <= 2) ? kq : (kq == 3 ? 3 : kq == 4 ? 5 : 8);
  const int cnt = (kq <= 2) ? 1  : (kq == 3 ? 2 : kq == 4 ? 3 : 5);

  __shared__ float sA[32][36];         // phase 1: A row-major; phase 2: G TRANSPOSED [col][row]
  __shared__ float sSc[32];

  for (int u = lane; u < 1024; u += 64) {
    float s = 0.f;
    for (int q = 0; q < cnt; ++q)
      s += part[((size_t)(s0 + q) * NBT + bt) * 1024 + u];
    sA[u >> 5][u & 31] = s;
  }
  __syncthreads();

  float g[16];
  #pragma unroll
  for (int i = 0; i < 16; ++i) g[i] = sA[16 * h + i][c];

  float n;
  {
    float p0 = 0.f, p1 = 0.f, p2 = 0.f, p3 = 0.f;
    #pragma unroll
    for (int e = 0; e < 16; e += 4) {
      p0 = fmaf(g[e + 0], g[e + 0], p0);
      p1 = fmaf(g[e + 1], g[e + 1], p1);
      p2 = fmaf(g[e + 2], g[e + 2], p2);
      p3 = fmaf(g[e + 3], g[e + 3], p3);
    }
    const float pp = (p0 + p1) + (p2 + p3);
    const float op = __shfl_xor(pp, 32);
    n = h ? (op + pp) : (pp + op);
  }

  const float EPS2 = 1e-6f;
  #pragma unroll 1
  for (int sweep = 0; sweep < 10; ++sweep) {
    int anybad = 0;
    #pragma unroll 1
    for (int m = 1; m < 32; ++m) {    // XOR pairing; m<32 keeps the half bit
      const int pidx = (lane ^ m) << 2;
      float tmp[16];
      #pragma unroll
      for (int e = 0; e < 16; ++e)
        tmp[e] = __int_as_float(__builtin_amdgcn_ds_bpermute(pidx, __float_as_int(g[e])));
      const float np = __int_as_float(__builtin_amdgcn_ds_bpermute(pidx, __float_as_int(n)));

      float d0 = 0.f, d1 = 0.f, d2 = 0.f, d3 = 0.f;
      #pragma unroll
      for (int e = 0; e < 16; e += 4) {
        d0 = fmaf(g[e + 0], tmp[e + 0], d0);
        d1 = fmaf(g[e + 1], tmp[e + 1], d1);
        d2 = fmaf(g[e + 2], tmp[e + 2], d2);
        d3 = fmaf(g[e + 3], tmp[e + 3], d3);
      }
      const float pp = (d0 + d1) + (d2 + d3);
      const float op = __shfl_xor(pp, 32);
      const float bpq = h ? (op + pp) : (pp + op);   // identical on all 4 pair lanes

      const int bad = (bpq * bpq > EPS2 * n * np);
      anybad |= bad;
      if (bad) {
        const float tau = (np - n) * 0.5f * __builtin_amdgcn_rcpf(bpq);
        float tf = __builtin_amdgcn_rcpf(fabsf(tau) + __builtin_amdgcn_sqrtf(fmaf(tau, tau, 1.f)));
        if (tau < 0.f) tf = -tf;
        const float cr = __builtin_amdgcn_rsqf(fmaf(tf, tf, 1.f));
        const float sg = -tf * cr;
        n = fmaf(-tf, bpq, n);
        #pragma unroll
        for (int e = 0; e < 16; ++e) g[e] = fmaf(sg, tmp[e], cr * g[e]);
      }
    }
    if (!__any(anybad)) break;
  }

  float nx;
  {
    float p0 = 0.f, p1 = 0.f, p2 = 0.f, p3 = 0.f;
    #pragma unroll
    for (int e = 0; e < 16; e += 4) {
      p0 = fmaf(g[e + 0], g[e + 0], p0);
      p1 = fmaf(g[e + 1], g[e + 1], p1);
      p2 = fmaf(g[e + 2], g[e + 2], p2);
      p3 = fmaf(g[e + 3], g[e + 3], p3);
    }
    const float pp = (p0 + p1) + (p2 + p3);
    const float op = __shfl_xor(pp, 32);
    nx = h ? (op + pp) : (pp + op);
  }
  const float lv = 0.5f * __logf(fmaxf(nx, 1.4210855e-10f));
  const float sc = (nx > 1e-32f) ? (lv * __builtin_amdgcn_rcpf(nx)) : 0.f;

  __syncthreads();                     // done with sA as A; reuse for G^T
  #pragma unroll
  for (int i = 0; i < 16; ++i) sA[c][16 * h + i] = g[i];
  if (h == 0) sSc[c] = sc;
  __syncthreads();

  float a[32];
  #pragma unroll
  for (int e = 0; e < 32; ++e) a[e] = sSc[e] * sA[e][c];   // sc_e * G[c][e]

  float* ob = eigTmp + ((size_t)blk * 1024 + c * 32 + 16 * h);
  #pragma unroll
  for (int q = 0; q < 4; ++q) {
    float4 acc = make_float4(0.f, 0.f, 0.f, 0.f);
    #pragma unroll
    for (int e = 0; e < 32; ++e) {
      const float4 gv = *(const float4*)&sA[e][16 * h + 4 * q];   // G[j..j+3][e], broadcast
      acc.x = fmaf(a[e], gv.x, acc.x);
      acc.y = fmaf(a[e], gv.y, acc.y);
      acc.z = fmaf(a[e], gv.z, acc.z);
      acc.w = fmaf(a[e], gv.w, acc.w);
    }
    *(float4*)(ob + 4 * q) = acc;
  }
}

// ---------------- K4: transpose (b,t,k,ij) -> out (b,k,ij,t) ----------------
__global__ __launch_bounds__(256) void k_tr(const float* __restrict__ eigTmp,
                                            float* __restrict__ out) {
  const int bk    = blockIdx.x >> 3;   // b*6 + k
  const int chunk = blockIdx.x & 7;
  const int b = bk / 6, k = bk % 6;
  const int ij0 = chunk * 128;
  const int tid = threadIdx.x;

  __shared__ float tile[128 * 59];

  for (int u = tid; u < 128 * NWIN; u += 256) {
    const int t = u >> 7, ijl = u & 127;
    tile[ijl * 59 + t] = eigTmp[((size_t)(b * NWIN + t) * 6 + k) * 1024 + ij0 + ijl];
  }
  __syncthreads();

  float* ob = out + ((size_t)bk * 1024 + ij0) * NWIN;
  for (int u = tid; u < 128 * NWIN; u += 256) {
    ob[u] = tile[(u / NWIN) * 59 + (u % NWIN)];
  }
}

extern "C" void kernel_launch(void* const* d_in, const int* in_sizes, int n_in,
                              void* d_out, int out_size, void* d_ws, size_t ws_size,
                              hipStream_t stream) {
  const float* x = (const float*)d_in[0];
  float* outp = (float*)d_out;

  const size_t SPEC_B = (size_t)8 * NFRM * NBIN * NC * sizeof(float2);   // 64.75 MB

  float2* spec   = (float2*)d_ws;
  float*  part   = (float*)((char*)d_ws + SPEC_B);   // 13 slots * 464 * 4KB = 24.7 MB
  float*  eigTmp = (float*)d_ws;       // reuses spec region (dead after k_csd)

  k_stft<<<dim3(8 * NFRM),  dim3(256), 0, stream>>>(x, spec);
  k_csd <<<dim3(NBT, 2),    dim3(256), 0, stream>>>(spec, part);
  k_eig <<<dim3(NMAT),      dim3(64),  0, stream>>>(part, eigTmp);
  k_tr  <<<dim3(48 * 8),    dim3(256), 0, stream>>>(eigTmp, outp);
}

// Round 20
// 386.743 us; speedup vs baseline: 3.7624x; 3.7624x over previous
//
#include <hip/hip_runtime.h>
#include <cstddef>

#define NFRM 247
#define NBIN 128
#define NC   32
#define NWIN 58
#define NMAT (8 * NWIN * 6)   // 2784
#define NBT  (8 * NWIN)       // 464

// ---------------- K1: STFT (16x16 split DFT, bins 1..128) ----------------
// R19 structure: block = (b, frame), 256 threads, 4 channel-groups of 8 in LDS.
// Twiddle-recurrence math (R13-proven). (f,ch)-tiled coalesced writes; XCD swizzle
// by b pins x[b] (2MB) in one L2. Y as re/im planes (odd stride 273).
// spec layout: (b, frame, f-1, c) float2 (unchanged for k_csd).
__global__ __launch_bounds__(256) void k_stft(const float* __restrict__ x,
                                              float2* __restrict__ spec) {
  const int bid = blockIdx.x;          // 8*247 blocks
  const int b   = bid & 7;             // batch -> XCD (bijective: 1976 = 8*247)
  const int fr  = bid >> 3;
  const int tid = threadIdx.x;

  __shared__ float w[256];
  __shared__ float xw[8][257];
  __shared__ float Yre[8][273];
  __shared__ float Yim[8][273];

  // hann window (np.hanning: periodic=False) * 1/||w||
  w[tid] = (0.5f - 0.5f * __cosf((float)tid * 0.024639942f)) * 0.10226200f;

  float2* ob = spec + ((size_t)b * NFRM + fr) * (NBIN * NC);
  const float* xb = x + ((size_t)b * 32) * 16000 + fr * 64;

  for (int g = 0; g < 4; ++g) {        // channel groups of 8
    __syncthreads();                   // w ready (g=0) / prev group done reading
    // load + window: xw[ch][t] = x[b][g*8+ch][fr*64+t] * w[t]
    #pragma unroll
    for (int k = 0; k < 8; ++k) {
      const int u = tid + k * 256;
      const int ch = u >> 8, t = u & 255;
      xw[ch][t] = xb[(size_t)(g * 8 + ch) * 16000 + t] * w[t];
    }
    __syncthreads();

    // stage A: Y[ch][e], e = 16*f0+t0 : sum_t1 xw[ch][16t1+t0] * e^{-i pi f0 t1/8}
    #pragma unroll
    for (int k = 0; k < 8; ++k) {
      const int u = tid + k * 256;
      const int ch = u >> 8;           // = k
      const int e = u & 255;
      const int f0 = e >> 4, t0 = e & 15;
      float sA, cA;
      __sincosf((float)f0 * 0.39269908f, &sA, &cA);   // pi/8
      float wr = 1.f, wi = 0.f, re = 0.f, im = 0.f;
      #pragma unroll
      for (int t1 = 0; t1 < 16; ++t1) {
        const float v = xw[ch][(t1 << 4) + t0];
        re = fmaf(v, wr, re);
        im = fmaf(v, wi, im);
        const float nwr = fmaf(wi, sA, wr * cA);
        const float nwi = fmaf(-wr, sA, wi * cA);
        wr = nwr; wi = nwi;
      }
      Yre[ch][e] = re;
      Yim[ch][e] = im;
    }
    __syncthreads();

    // stage B + write: job j = (f-1)*8 + ch; f = (j>>3)+1, ch = j&7
    #pragma unroll
    for (int q = 0; q < 4; ++q) {
      const int j = tid + q * 256;
      const int ch = j & 7;
      const int f = (j >> 3) + 1;      // 1..128
      const int f0 = f & 15;
      float sB, cB;
      __sincosf((float)f * 0.024543693f, &sB, &cB);   // 2pi/256
      float wr = 1.f, wi = 0.f, re = 0.f, im = 0.f;
      #pragma unroll
      for (int t0 = 0; t0 < 16; ++t0) {
        const float yr = Yre[ch][(f0 << 4) + t0];
        const float yi = Yim[ch][(f0 << 4) + t0];
        re += yr * wr - yi * wi;
        im += yr * wi + yi * wr;
        const float nwr = fmaf(wi, sB, wr * cB);
        const float nwi = fmaf(-wr, sB, wi * cB);
        wr = nwr; wi = nwi;
      }
      ob[(size_t)(f - 1) * NC + g * 8 + ch] = make_float2(re, im);
    }
  }
}

// ---------------- K2: CSD + |.|^2 + band-slot partials ----------------
// R18-PROVEN version, byte-identical (157us, VGPR 168). R19's __launch_bounds__(256,4)
// forced VGPR 168->64 -> 2.8GB scratch spill -> 1057us. NO register cap.
// part layout: (slot, bt, i*32+j) float.
__global__ __launch_bounds__(256) void k_csd(const float2* __restrict__ spec,
                                             float* __restrict__ part) {
  const int bt  = (blockIdx.x & 7) * 58 + (blockIdx.x >> 3);   // b*58 + t (swizzled)
  const int p   = blockIdx.y;          // f-half: 0 -> f 1..64, 1 -> f 65..128
  const int b   = bt / NWIN, t = bt % NWIN;
  const int tid = threadIdx.x;
  const int wv  = tid >> 6;            // wave 0..3
  const int lane = tid & 63;
  const int i0 = (lane >> 3) * 4;
  const int j0 = (lane & 7) * 4;

  __shared__ __align__(16) float2 rng[4][2][512];   // 32KB wave-private ring

  float bacc[16];
  #pragma unroll
  for (int e = 0; e < 16; ++e) bacc[e] = 0.f;

  const float2* sb = spec + (size_t)b * NFRM * NBIN * NC;
  const int fbase = 1 + 64 * p + 16 * wv;           // wave's first bin
  int slot = p ? (9 + wv) : (wv == 0 ? 0 : wv == 1 ? 4 : wv == 2 ? 6 : 7);

  #define BANDOF(f) ((f) <= 3 ? 0 : (f) <= 6 ? 1 : (f) <= 12 ? 2 : (f) <= 25 ? 3 : (f) <= 51 ? 4 : 5)
  int curband = BANDOF(fbase);

  #define FLUSH()                                                                \
    {                                                                            \
      float scl_;                                                                \
      switch (curband) {                                                         \
        case 0: case 1: scl_ = 1.f / 768.f;   break;                             \
        case 2:         scl_ = 1.f / 1536.f;  break;                             \
        case 3:         scl_ = 1.f / 3328.f;  break;                             \
        case 4:         scl_ = 1.f / 6656.f;  break;                             \
        default:        scl_ = 1.f / 19712.f; break;                             \
      }                                                                          \
      float* op_ = part + ((size_t)slot * NBT + bt) * 1024;                      \
      _Pragma("unroll")                                                          \
      for (int a = 0; a < 4; ++a)                                                \
        *(float4*)(op_ + (i0 + a) * 32 + j0) =                                   \
          make_float4(bacc[a * 4 + 0] * scl_, bacc[a * 4 + 1] * scl_,            \
                      bacc[a * 4 + 2] * scl_, bacc[a * 4 + 3] * scl_);           \
      _Pragma("unroll")                                                          \
      for (int e = 0; e < 16; ++e) bacc[e] = 0.f;                                \
    }

  #define STG_LOAD(itl, dst)                                                     \
    {                                                                            \
      const int f_ = fbase + (itl);                                              \
      const float2* fp_ = sb + (size_t)(f_ - 1) * NC;                            \
      _Pragma("unroll")                                                          \
      for (int r = 0; r < 8; ++r) {                                              \
        const int e_ = lane + r * 64;                                            \
        dst[r] = fp_[(size_t)(t * 4 + (e_ >> 5)) * (NBIN * NC) + (e_ & 31)];     \
      }                                                                          \
    }

  // prologue: stage itl=0
  {
    float2 stg[8];
    STG_LOAD(0, stg)
    #pragma unroll
    for (int r = 0; r < 8; ++r) rng[wv][0][lane + r * 64] = stg[r];
  }

  #pragma unroll 1
  for (int itl = 0; itl < 16; ++itl) {
    float2 stg2[8];
    if (itl + 1 < 16) STG_LOAD(itl + 1, stg2)

    const int f = fbase + itl;                       // wave-uniform bin
    if (f == 4 || f == 7 || f == 13 || f == 26 || f == 52) {   // band crossing
      FLUSH()
      ++slot;
      curband = BANDOF(f);
    }

    const float2* Xs = rng[wv][itl & 1];

    float accRe[16], accIm[16];
    #pragma unroll
    for (int e = 0; e < 16; ++e) { accRe[e] = 0.f; accIm[e] = 0.f; }

    #pragma unroll
    for (int s = 0; s < 16; ++s) {
      float2 xi[4], xj[4];
      #pragma unroll
      for (int a = 0; a < 4; ++a) {
        xi[a] = Xs[s * 32 + i0 + a];
        xj[a] = Xs[s * 32 + j0 + a];
      }
      #pragma unroll
      for (int a = 0; a < 4; ++a)
        #pragma unroll
        for (int d = 0; d < 4; ++d) {
          const int e = a * 4 + d;
          // M_ij += x_i * conj(x_j)
          accRe[e] = fmaf(xi[a].x, xj[d].x, fmaf(xi[a].y, xj[d].y, accRe[e]));
          accIm[e] = fmaf(xi[a].y, xj[d].x, fmaf(-xi[a].x, xj[d].y, accIm[e]));
        }
    }

    #pragma unroll
    for (int e = 0; e < 16; ++e)
      bacc[e] = fmaf(accRe[e], accRe[e], fmaf(accIm[e], accIm[e], bacc[e]));

    if (itl + 1 < 16) {
      #pragma unroll
      for (int r = 0; r < 8; ++r) rng[wv][(itl + 1) & 1][lane + r * 64] = stg2[r];
    }
  }
  FLUSH()   // final band
  #undef STG_LOAD
  #undef FLUSH
  #undef BANDOF
}

// ---------------- K3: one-sided Jacobi eig + matrix log ----------------
// R12/R15-proven core (bpermute exchange). EPS2=1e-6 [R18-validated, absmax 0.0156].
// Slot sums in fixed order (deterministic).
__global__ __launch_bounds__(64) void k_eig(const float* __restrict__ part,
                                            float* __restrict__ eigTmp) {
  const int blk  = blockIdx.x;         // matrix id = (b*58+t)*6 + k
  const int lane = threadIdx.x;
  const int h    = lane >> 5;          // half: rows [16h, 16h+16)
  const int c    = lane & 31;          // column

  const int kq = blk % 6;
  const int bt = blk / 6;
  const int s0  = (kq <= 2) ? kq : (kq == 3 ? 3 : kq == 4 ? 5 : 8);
  const int cnt = (kq <= 2) ? 1  : (kq == 3 ? 2 : kq == 4 ? 3 : 5);

  __shared__ float sA[32][36];         // phase 1: A row-major; phase 2: G TRANSPOSED [col][row]
  __shared__ float sSc[32];

  for (int u = lane; u < 1024; u += 64) {
    float s = 0.f;
    for (int q = 0; q < cnt; ++q)
      s += part[((size_t)(s0 + q) * NBT + bt) * 1024 + u];
    sA[u >> 5][u & 31] = s;
  }
  __syncthreads();

  float g[16];
  #pragma unroll
  for (int i = 0; i < 16; ++i) g[i] = sA[16 * h + i][c];

  float n;
  {
    float p0 = 0.f, p1 = 0.f, p2 = 0.f, p3 = 0.f;
    #pragma unroll
    for (int e = 0; e < 16; e += 4) {
      p0 = fmaf(g[e + 0], g[e + 0], p0);
      p1 = fmaf(g[e + 1], g[e + 1], p1);
      p2 = fmaf(g[e + 2], g[e + 2], p2);
      p3 = fmaf(g[e + 3], g[e + 3], p3);
    }
    const float pp = (p0 + p1) + (p2 + p3);
    const float op = __shfl_xor(pp, 32);
    n = h ? (op + pp) : (pp + op);
  }

  const float EPS2 = 1e-6f;
  #pragma unroll 1
  for (int sweep = 0; sweep < 10; ++sweep) {
    int anybad = 0;
    #pragma unroll 1
    for (int m = 1; m < 32; ++m) {    // XOR pairing; m<32 keeps the half bit
      const int pidx = (lane ^ m) << 2;
      float tmp[16];
      #pragma unroll
      for (int e = 0; e < 16; ++e)
        tmp[e] = __int_as_float(__builtin_amdgcn_ds_bpermute(pidx, __float_as_int(g[e])));
      const float np = __int_as_float(__builtin_amdgcn_ds_bpermute(pidx, __float_as_int(n)));

      float d0 = 0.f, d1 = 0.f, d2 = 0.f, d3 = 0.f;
      #pragma unroll
      for (int e = 0; e < 16; e += 4) {
        d0 = fmaf(g[e + 0], tmp[e + 0], d0);
        d1 = fmaf(g[e + 1], tmp[e + 1], d1);
        d2 = fmaf(g[e + 2], tmp[e + 2], d2);
        d3 = fmaf(g[e + 3], tmp[e + 3], d3);
      }
      const float pp = (d0 + d1) + (d2 + d3);
      const float op = __shfl_xor(pp, 32);
      const float bpq = h ? (op + pp) : (pp + op);   // identical on all 4 pair lanes

      const int bad = (bpq * bpq > EPS2 * n * np);
      anybad |= bad;
      if (bad) {
        const float tau = (np - n) * 0.5f * __builtin_amdgcn_rcpf(bpq);
        float tf = __builtin_amdgcn_rcpf(fabsf(tau) + __builtin_amdgcn_sqrtf(fmaf(tau, tau, 1.f)));
        if (tau < 0.f) tf = -tf;
        const float cr = __builtin_amdgcn_rsqf(fmaf(tf, tf, 1.f));
        const float sg = -tf * cr;
        n = fmaf(-tf, bpq, n);
        #pragma unroll
        for (int e = 0; e < 16; ++e) g[e] = fmaf(sg, tmp[e], cr * g[e]);
      }
    }
    if (!__any(anybad)) break;
  }

  float nx;
  {
    float p0 = 0.f, p1 = 0.f, p2 = 0.f, p3 = 0.f;
    #pragma unroll
    for (int e = 0; e < 16; e += 4) {
      p0 = fmaf(g[e + 0], g[e + 0], p0);
      p1 = fmaf(g[e + 1], g[e + 1], p1);
      p2 = fmaf(g[e + 2], g[e + 2], p2);
      p3 = fmaf(g[e + 3], g[e + 3], p3);
    }
    const float pp = (p0 + p1) + (p2 + p3);
    const float op = __shfl_xor(pp, 32);
    nx = h ? (op + pp) : (pp + op);
  }
  const float lv = 0.5f * __logf(fmaxf(nx, 1.4210855e-10f));
  const float sc = (nx > 1e-32f) ? (lv * __builtin_amdgcn_rcpf(nx)) : 0.f;

  __syncthreads();                     // done with sA as A; reuse for G^T
  #pragma unroll
  for (int i = 0; i < 16; ++i) sA[c][16 * h + i] = g[i];
  if (h == 0) sSc[c] = sc;
  __syncthreads();

  float a[32];
  #pragma unroll
  for (int e = 0; e < 32; ++e) a[e] = sSc[e] * sA[e][c];   // sc_e * G[c][e]

  float* ob = eigTmp + ((size_t)blk * 1024 + c * 32 + 16 * h);
  #pragma unroll
  for (int q = 0; q < 4; ++q) {
    float4 acc = make_float4(0.f, 0.f, 0.f, 0.f);
    #pragma unroll
    for (int e = 0; e < 32; ++e) {
      const float4 gv = *(const float4*)&sA[e][16 * h + 4 * q];   // G[j..j+3][e], broadcast
      acc.x = fmaf(a[e], gv.x, acc.x);
      acc.y = fmaf(a[e], gv.y, acc.y);
      acc.z = fmaf(a[e], gv.z, acc.z);
      acc.w = fmaf(a[e], gv.w, acc.w);
    }
    *(float4*)(ob + 4 * q) = acc;
  }
}

// ---------------- K4: transpose (b,t,k,ij) -> out (b,k,ij,t) ----------------
__global__ __launch_bounds__(256) void k_tr(const float* __restrict__ eigTmp,
                                            float* __restrict__ out) {
  const int bk    = blockIdx.x >> 3;   // b*6 + k
  const int chunk = blockIdx.x & 7;
  const int b = bk / 6, k = bk % 6;
  const int ij0 = chunk * 128;
  const int tid = threadIdx.x;

  __shared__ float tile[128 * 59];

  for (int u = tid; u < 128 * NWIN; u += 256) {
    const int t = u >> 7, ijl = u & 127;
    tile[ijl * 59 + t] = eigTmp[((size_t)(b * NWIN + t) * 6 + k) * 1024 + ij0 + ijl];
  }
  __syncthreads();

  float* ob = out + ((size_t)bk * 1024 + ij0) * NWIN;
  for (int u = tid; u < 128 * NWIN; u += 256) {
    ob[u] = tile[(u / NWIN) * 59 + (u % NWIN)];
  }
}

extern "C" void kernel_launch(void* const* d_in, const int* in_sizes, int n_in,
                              void* d_out, int out_size, void* d_ws, size_t ws_size,
                              hipStream_t stream) {
  const float* x = (const float*)d_in[0];
  float* outp = (float*)d_out;

  const size_t SPEC_B = (size_t)8 * NFRM * NBIN * NC * sizeof(float2);   // 64.75 MB

  float2* spec   = (float2*)d_ws;
  float*  part   = (float*)((char*)d_ws + SPEC_B);   // 13 slots * 464 * 4KB = 24.7 MB
  float*  eigTmp = (float*)d_ws;       // reuses spec region (dead after k_csd)

  k_stft<<<dim3(8 * NFRM),  dim3(256), 0, stream>>>(x, spec);
  k_csd <<<dim3(NBT, 2),    dim3(256), 0, stream>>>(spec, part);
  k_eig <<<dim3(NMAT),      dim3(64),  0, stream>>>(part, eigTmp);
  k_tr  <<<dim3(48 * 8),    dim3(256), 0, stream>>>(eigTmp, outp);
}